// Round 2
// baseline (2026.728 us; speedup 1.0000x reference)
//
#include <hip/hip_runtime.h>

// 2-layer stacked LSTM (shared cell), B=256, T=1024, F=UNITS=128.
// One WG (512 thr) per batch element, 256 WGs = 1/CU. Fused-tick schedule:
// tick k computes cell1 step k AND cell2 step k-1 (independent given h1[k-1])
// -> one barrier per tick, overlapped epilogues.
// Thread map: u = wave*16 + (lane&15) in [0,128), ks = lane>>4 in [0,4).
// Thread owns the 4 gate columns {u, u+128, u+256, u+384} over k-slice
// [32ks, 32ks+32). k-reduction = 2 shfl_xor rounds in-wave. Gate math
// redundant across the 4 ks lanes; c1/c2 kept redundantly in registers.
//
// d_out layout (f32): [0,32768) h2_final | [32768,+33554432) zeros
//                     | [33587200,33619968) c1_final

typedef _Float16 h16;
typedef _Float16 h16x2 __attribute__((ext_vector_type(2)));

#define T_STEPS 1024
#define UNITS   128

__device__ __forceinline__ float fdot2(h16x2 a, h16x2 b, float c) {
#if __has_builtin(__builtin_amdgcn_fdot2)
    return __builtin_amdgcn_fdot2(a, b, c, false);
#else
    float d;
    asm("v_dot2_f32_f16 %0, %1, %2, %3" : "=v"(d) : "v"(a), "v"(b), "v"(c));
    return d;
#endif
}

__device__ __forceinline__ float frcp_(float x) {
#if __has_builtin(__builtin_amdgcn_rcpf)
    return __builtin_amdgcn_rcpf(x);
#else
    return 1.0f / x;
#endif
}
__device__ __forceinline__ float sigmoidf_(float x) {
    return frcp_(1.0f + __expf(-x));
}
__device__ __forceinline__ float tanhf_(float x) {
    float e = __expf(2.0f * x);
    return 1.0f - 2.0f * frcp_(e + 1.0f);
}

__global__ __launch_bounds__(512, 2) void lstm2_kernel(
    const float* __restrict__ X,   // [256][1024][128]
    const float* __restrict__ W,   // [128][512]  gate order i|f|g|o
    const float* __restrict__ U,   // [128][512]
    const float* __restrict__ Bv,  // [512]
    float* __restrict__ out)
{
    const int tid  = threadIdx.x;
    const int wave = tid >> 6;
    const int lane = tid & 63;
    const int u    = wave * 16 + (lane & 15);   // unit in [0,128)
    const int ks   = lane >> 4;                 // k-slice in [0,4)
    const int k0   = ks * 32;
    const int b    = blockIdx.x;
    const size_t xbase = (size_t)b * (T_STEPS * UNITS);

    __shared__ __align__(16) h16 xbuf[2][UNITS];
    __shared__ __align__(16) h16 h1buf[2][UNITS];
    __shared__ __align__(16) h16 h2buf[2][UNITS];

    // ---- weights into registers: f16 pairs along K; 128 VGPRs of weights
    h16x2 wW[16][4], wU[16][4];
    #pragma unroll
    for (int kk = 0; kk < 16; ++kk) {
        const int k = k0 + 2 * kk;
        #pragma unroll
        for (int c = 0; c < 4; ++c) {
            const int col = u + c * 128;
            h16x2 w, uu;
            w[0]  = (h16)W[(size_t)k * 512 + col];
            w[1]  = (h16)W[(size_t)(k + 1) * 512 + col];
            uu[0] = (h16)U[(size_t)k * 512 + col];
            uu[1] = (h16)U[(size_t)(k + 1) * 512 + col];
            wW[kk][c] = w;  wU[kk][c] = uu;
        }
    }
    float bias[4];
    #pragma unroll
    for (int c = 0; c < 4; ++c) bias[c] = Bv[u + c * 128];

    if (ks == 0) {
        h1buf[0][u] = (h16)0.0f;  h1buf[1][u] = (h16)0.0f;
        h2buf[0][u] = (h16)0.0f;  h2buf[1][u] = (h16)0.0f;
        xbuf[0][u]  = (h16)X[xbase + u];
    }
    __syncthreads();

    float c1 = 0.0f, c2 = 0.0f, h1v = 0.0f, h2v = 0.0f;
    const float* xin  = X + xbase + u;                    // ks==0 lanes prefetch
    float*       zout = out + 32768 + xbase + u;          // zeros output slice

    for (int k = 0; k <= T_STEPS; ++k) {
        const int rd = k & 1, wr = rd ^ 1;

        // prefetch x[k+1]; ~1600 cyc of tick work covers the HBM latency
        float xn = 0.0f;
        if (ks == 0 && k + 1 < T_STEPS) xn = xin[(size_t)(k + 1) * UNITS];

        // load this tick's x/h slices (broadcast b128 reads, <=2-way banks)
        const uint4* xb  = (const uint4*)xbuf[rd];
        const uint4* h1b = (const uint4*)h1buf[rd];
        const uint4* h2b = (const uint4*)h2buf[rd];
        uint4 xv[4], av[4], bvv[4];
        #pragma unroll
        for (int q = 0; q < 4; ++q) {
            xv[q]  = xb[ks * 4 + q];
            av[q]  = h1b[ks * 4 + q];
            bvv[q] = h2b[ks * 4 + q];
        }

        // ---- fused dot phase: z1 = x@W + h1@U ; z2 = h1@W + h2@U
        float z1[4] = {0.f, 0.f, 0.f, 0.f}, z2[4] = {0.f, 0.f, 0.f, 0.f};
        #pragma unroll
        for (int q = 0; q < 4; ++q) {
            const unsigned* xw = (const unsigned*)&xv[q];
            const unsigned* aw = (const unsigned*)&av[q];
            const unsigned* bw = (const unsigned*)&bvv[q];
            #pragma unroll
            for (int p = 0; p < 4; ++p) {
                h16x2 xp = __builtin_bit_cast(h16x2, xw[p]);
                h16x2 ap = __builtin_bit_cast(h16x2, aw[p]);
                h16x2 bp = __builtin_bit_cast(h16x2, bw[p]);
                const int kk = q * 4 + p;
                #pragma unroll
                for (int c = 0; c < 4; ++c) {
                    z1[c] = fdot2(xp, wW[kk][c], z1[c]);
                    z1[c] = fdot2(ap, wU[kk][c], z1[c]);
                    z2[c] = fdot2(ap, wW[kk][c], z2[c]);
                    z2[c] = fdot2(bp, wU[kk][c], z2[c]);
                }
            }
        }

        // ---- in-wave k-reduction over the 4 ks lanes (butterfly)
        #pragma unroll
        for (int c = 0; c < 4; ++c) {
            z1[c] += __shfl_xor(z1[c], 16);
            z1[c] += __shfl_xor(z1[c], 32);
            z1[c] += bias[c];
            z2[c] += __shfl_xor(z2[c], 16);
            z2[c] += __shfl_xor(z2[c], 32);
            z2[c] += bias[c];
        }

        // ---- gate math, redundant in all 4 ks lanes (wave-uniform guards)
        if (k < T_STEPS) {
            float i1 = sigmoidf_(z1[0]), f1 = sigmoidf_(z1[1]);
            float g1 = tanhf_(z1[2]),    o1 = sigmoidf_(z1[3]);
            c1  = f1 * c1 + i1 * g1;
            h1v = o1 * tanhf_(c1);
        }
        if (k > 0) {
            float i2 = sigmoidf_(z2[0]), f2 = sigmoidf_(z2[1]);
            float g2 = tanhf_(z2[2]),    o2 = sigmoidf_(z2[3]);
            c2  = f2 * c2 + i2 * g2;
            h2v = o2 * tanhf_(c2);
        }

        if (ks == 0) {
            if (k < T_STEPS) {
                h1buf[wr][u] = (h16)h1v;
                zout[(size_t)k * UNITS] = 0.0f;   // zeros output, coalesced
            }
            if (k > 0)            h2buf[wr][u] = (h16)h2v;
            if (k + 1 < T_STEPS)  xbuf[wr][u]  = (h16)xn;
        }
        __syncthreads();
    }

    if (ks == 0) {
        out[b * UNITS + u] = h2v;                          // h2 final
        out[(size_t)33587200 + b * UNITS + u] = c1;        // c1 final
    }
}

extern "C" void kernel_launch(void* const* d_in, const int* in_sizes, int n_in,
                              void* d_out, int out_size, void* d_ws, size_t ws_size,
                              hipStream_t stream) {
    const float* X  = (const float*)d_in[0];
    const float* W  = (const float*)d_in[1];
    const float* U  = (const float*)d_in[2];
    const float* Bv = (const float*)d_in[3];
    float* out = (float*)d_out;
    hipLaunchKernelGGL(lstm2_kernel, dim3(256), dim3(512), 0, stream,
                       X, W, U, Bv, out);
}

// Round 3
// 1850.103 us; speedup vs baseline: 1.0955x; 1.0955x over previous
//
#include <hip/hip_runtime.h>

// 2-layer stacked LSTM (shared cell), B=256, T=1024, F=UNITS=128.
// 1024 threads/WG, one WG per batch element (256 WGs = 1/CU).
// Fused tick k: cell1 step k AND cell2 step k-1. Two barriers per tick.
//
// Thread map: wave = tid>>6 (16 waves), half = wave>>3, uhi = wave&7,
//   u = uhi*16 + (lane&15) in [0,128), ks = lane>>4 in [0,4).
// Thread owns 2 gate columns {u + 2*half*128, u + (2*half+1)*128} over
// k-slice [32ks, 32ks+32): 64 h16x2 weight VGPRs (fits 128-reg budget at
// 4 waves/SIMD). k-reduce in-wave via shfl_xor(16/32); {g,o} gates cross
// from waves 8-15 to the gate-math threads via zlds[128][4] (float4,
// 2-way banks = free).
//
// d_out layout (f32): [0,32768) h2_final | [32768,+33554432) zeros
//                     | [33587200,33619968) c1_final

typedef _Float16 h16;
typedef _Float16 h16x2 __attribute__((ext_vector_type(2)));

#define T_STEPS 1024
#define UNITS   128

__device__ __forceinline__ float fdot2(h16x2 a, h16x2 b, float c) {
#if __has_builtin(__builtin_amdgcn_fdot2)
    return __builtin_amdgcn_fdot2(a, b, c, false);
#else
    float d;
    asm("v_dot2_f32_f16 %0, %1, %2, %3" : "=v"(d) : "v"(a), "v"(b), "v"(c));
    return d;
#endif
}

__device__ __forceinline__ float frcp_(float x) {
#if __has_builtin(__builtin_amdgcn_rcpf)
    return __builtin_amdgcn_rcpf(x);
#else
    return 1.0f / x;
#endif
}
__device__ __forceinline__ float sigmoidf_(float x) {
    return frcp_(1.0f + __expf(-x));
}
__device__ __forceinline__ float tanhf_(float x) {
    float e = __expf(2.0f * x);
    return 1.0f - 2.0f * frcp_(e + 1.0f);
}

__global__ __launch_bounds__(1024, 4) void lstm2_kernel(
    const float* __restrict__ X,   // [256][1024][128]
    const float* __restrict__ W,   // [128][512]  gate order i|f|g|o
    const float* __restrict__ U,   // [128][512]
    const float* __restrict__ Bv,  // [512]
    float* __restrict__ out)
{
    const int tid  = threadIdx.x;
    const int wave = tid >> 6;
    const int lane = tid & 63;
    const int half = wave >> 3;                 // 0: {i,f} cols, 1: {g,o}
    const int u    = (wave & 7) * 16 + (lane & 15);
    const int ks   = lane >> 4;
    const int colA = u + (2 * half) * 128;
    const int colB = colA + 128;
    const int k0   = ks * 32;
    const int b    = blockIdx.x;
    const size_t xbase = (size_t)b * (T_STEPS * UNITS);

    __shared__ __align__(16) h16   xbuf[2][UNITS];
    __shared__ __align__(16) h16   h1buf[2][UNITS];
    __shared__ __align__(16) h16   h2buf[2][UNITS];
    __shared__ __align__(16) float zlds[UNITS][4];   // g1,o1,g2,o2 per unit

    // ---- weights to registers: 64 h16x2 (2 cols x 2 mats x 16 k-pairs)
    h16x2 wAW[16], wAU[16], wBW[16], wBU[16];
    #pragma unroll
    for (int kk = 0; kk < 16; ++kk) {
        const int k = k0 + 2 * kk;
        h16x2 t;
        t[0] = (h16)W[(size_t)k * 512 + colA]; t[1] = (h16)W[(size_t)(k + 1) * 512 + colA]; wAW[kk] = t;
        t[0] = (h16)W[(size_t)k * 512 + colB]; t[1] = (h16)W[(size_t)(k + 1) * 512 + colB]; wBW[kk] = t;
        t[0] = (h16)U[(size_t)k * 512 + colA]; t[1] = (h16)U[(size_t)(k + 1) * 512 + colA]; wAU[kk] = t;
        t[0] = (h16)U[(size_t)k * 512 + colB]; t[1] = (h16)U[(size_t)(k + 1) * 512 + colB]; wBU[kk] = t;
    }
    const float biasA = Bv[colA], biasB = Bv[colB];

    if (tid < UNITS) {
        h1buf[0][tid] = (h16)0.0f;  h1buf[1][tid] = (h16)0.0f;
        h2buf[0][tid] = (h16)0.0f;  h2buf[1][tid] = (h16)0.0f;
        xbuf[0][tid]  = (h16)X[xbase + tid];
    }
    __syncthreads();

    const bool is_gate   = (half == 0) && (ks == 0);  // gate math + h writes
    const bool is_zwrite = (half == 1) && (ks == 0);  // publish g/o pre-acts
    const bool is_xpre   = (half == 0) && (ks == 1);  // x prefetch
    const bool is_zero   = (half == 1) && (ks == 1);  // zeros output

    float c1 = 0.0f, c2 = 0.0f, h2v = 0.0f;

    for (int k = 0; k <= T_STEPS; ++k) {
        const int rd = k & 1, wr = rd ^ 1;

        // issue x[k+1] prefetch early; ds_write happens after barrier 1
        float xn = 0.0f;
        if (is_xpre && k + 1 < T_STEPS) xn = X[xbase + (size_t)(k + 1) * UNITS + u];
        if (is_zero && k < T_STEPS) out[(size_t)32768 + xbase + (size_t)k * UNITS + u] = 0.0f;

        const uint4* xb = (const uint4*)xbuf[rd];
        const uint4* ab = (const uint4*)h1buf[rd];
        const uint4* bb = (const uint4*)h2buf[rd];

        // ---- dot phase: z1 = x@W + h1@U ; z2 = h1@W + h2@U (2 cols each)
        float z1A = 0.f, z1B = 0.f, z2A = 0.f, z2B = 0.f;
        #pragma unroll
        for (int q = 0; q < 4; ++q) {
            const uint4 xv = xb[ks * 4 + q];
            const uint4 av = ab[ks * 4 + q];
            const uint4 bv = bb[ks * 4 + q];
            const unsigned* xw = (const unsigned*)&xv;
            const unsigned* aw = (const unsigned*)&av;
            const unsigned* bw = (const unsigned*)&bv;
            #pragma unroll
            for (int p = 0; p < 4; ++p) {
                const h16x2 xp = __builtin_bit_cast(h16x2, xw[p]);
                const h16x2 ap = __builtin_bit_cast(h16x2, aw[p]);
                const h16x2 bp = __builtin_bit_cast(h16x2, bw[p]);
                const int kk = q * 4 + p;
                z1A = fdot2(xp, wAW[kk], z1A);
                z1A = fdot2(ap, wAU[kk], z1A);
                z1B = fdot2(xp, wBW[kk], z1B);
                z1B = fdot2(ap, wBU[kk], z1B);
                z2A = fdot2(ap, wAW[kk], z2A);
                z2A = fdot2(bp, wAU[kk], z2A);
                z2B = fdot2(ap, wBW[kk], z2B);
                z2B = fdot2(bp, wBU[kk], z2B);
            }
        }

        // ---- k-reduce across the 4 ks lanes (in-wave butterfly)
        z1A += __shfl_xor(z1A, 16);  z1A += __shfl_xor(z1A, 32);  z1A += biasA;
        z1B += __shfl_xor(z1B, 16);  z1B += __shfl_xor(z1B, 32);  z1B += biasB;
        z2A += __shfl_xor(z2A, 16);  z2A += __shfl_xor(z2A, 32);  z2A += biasA;
        z2B += __shfl_xor(z2B, 16);  z2B += __shfl_xor(z2B, 32);  z2B += biasB;

        if (is_zwrite)   // half==1: A=g-col, B=o-col
            *(float4*)&zlds[u][0] = make_float4(z1A, z1B, z2A, z2B);
        __syncthreads();

        if (is_gate) {   // half==0: A=i-col, B=f-col
            const float4 go = *(const float4*)&zlds[u][0];
            if (k < T_STEPS) {
                float i1 = sigmoidf_(z1A), f1 = sigmoidf_(z1B);
                float g1 = tanhf_(go.x),   o1 = sigmoidf_(go.y);
                c1 = f1 * c1 + i1 * g1;
                h1buf[wr][u] = (h16)(o1 * tanhf_(c1));
                if (k == T_STEPS - 1) out[(size_t)33587200 + b * UNITS + u] = c1;
            }
            if (k > 0) {
                float i2 = sigmoidf_(z2A), f2 = sigmoidf_(z2B);
                float g2 = tanhf_(go.z),   o2 = sigmoidf_(go.w);
                c2  = f2 * c2 + i2 * g2;
                h2v = o2 * tanhf_(c2);
                if (k < T_STEPS) h2buf[wr][u] = (h16)h2v;
                else             out[b * UNITS + u] = h2v;   // h2 final
            }
        }
        if (is_xpre && k + 1 < T_STEPS) xbuf[wr][u] = (h16)xn;
        __syncthreads();
    }
}

extern "C" void kernel_launch(void* const* d_in, const int* in_sizes, int n_in,
                              void* d_out, int out_size, void* d_ws, size_t ws_size,
                              hipStream_t stream) {
    const float* X  = (const float*)d_in[0];
    const float* W  = (const float*)d_in[1];
    const float* U  = (const float*)d_in[2];
    const float* Bv = (const float*)d_in[3];
    float* out = (float*)d_out;
    hipLaunchKernelGGL(lstm2_kernel, dim3(256), dim3(1024), 0, stream,
                       X, W, U, Bv, out);
}

// Round 4
// 1186.421 us; speedup vs baseline: 1.7083x; 1.5594x over previous
//
#include <hip/hip_runtime.h>

// 2-layer stacked LSTM (shared cell), B=256, T=1024, F=UNITS=128 — MFMA version.
// 32 LSTM WGs (512 thr, 8 waves) x 8 batch rows; blocks 32..255 fill the zeros
// output in parallel on otherwise-idle CUs.
//
// Per tick k (fused): z1 = x[k]@W + h1[k-1]@U (cell1 step k),
//                     z2 = h1[k-1]@W + h2[k-2]@U (cell2 step k-1).
// Both cells packed into M: A1 = [x; h1'] (rows 0-15), A2 = [h1'; h2']
// (rows 8-23 of the same LDS buffer). acc rows 0-7 = z1, rows 8-15 = z2.
// Wave w owns unit block [16w,16w+16) and its 4 gate columns {u+128g}:
// epilogue is lane-local on acc (C: col=lane&15, row=4*(lane>>4)+e);
// lanes<32 do cell1, lanes>=32 do cell2 — same instruction stream.
// Weights stay resident as 128 B-fragment VGPRs (MFMA reads AGPRs natively,
// so compiler demotion costs nothing). One barrier per tick.
//
// LDS: A[2][24 rows][256B f16], XOR-swizzled (byte ^= (row&7)<<4).
// d_out (f32): [0,32768) h2_final | [32768,+33554432) zeros | [33587200,..) c1

typedef _Float16 f16;
typedef _Float16 f16x2 __attribute__((ext_vector_type(2)));
typedef _Float16 f16x8 __attribute__((ext_vector_type(8)));
typedef float    f32x4 __attribute__((ext_vector_type(4)));

#define T_STEPS 1024
#define UNITS   128
#define NB      32      // LSTM workgroups
#define BPW     8       // batch rows per LSTM WG
#define NBLK    256     // total grid
#define OUT_ZERO 32768
#define OUT_C1   33587200
#define BUFB     6144   // bytes per A buffer (24 rows * 256B)

__device__ __forceinline__ float frcp_(float x) {
#if __has_builtin(__builtin_amdgcn_rcpf)
    return __builtin_amdgcn_rcpf(x);
#else
    return 1.0f / x;
#endif
}
__device__ __forceinline__ float sigmoidf_(float x) {
    return frcp_(1.0f + __expf(-x));
}
__device__ __forceinline__ float tanhf_(float x) {
    float e = __expf(2.0f * x);
    return 1.0f - 2.0f * frcp_(e + 1.0f);
}
__device__ __forceinline__ unsigned pkh(float a, float b) {
    f16x2 t; t[0] = (f16)a; t[1] = (f16)b;
    return __builtin_bit_cast(unsigned, t);
}

__global__ __launch_bounds__(512, 2) void lstm2_kernel(
    const float* __restrict__ X,   // [256][1024][128]
    const float* __restrict__ W,   // [128][512] gate order i|f|g|o
    const float* __restrict__ U,   // [128][512]
    const float* __restrict__ Bv,  // [512]
    float* __restrict__ out)
{
    const int blk = blockIdx.x;
    const int tid = threadIdx.x;

    if (blk >= NB) {
        // ---------- zeros-output fill on idle CUs ----------
        const size_t nthr = (size_t)(NBLK - NB) * 512;
        float4* dst = (float4*)(out + OUT_ZERO);
        const float4 z4 = make_float4(0.f, 0.f, 0.f, 0.f);
        for (size_t i = (size_t)(blk - NB) * 512 + tid; i < 8388608u; i += nthr)
            dst[i] = z4;
        return;
    }

    // ---------- LSTM workgroup ----------
    const int wv = tid >> 6;        // wave = unit block
    const int l  = tid & 63;
    const int lr = l & 15;          // A row / C col (unit within block)
    const int lc = l >> 4;          // k-chunk / C row group
    const int u  = wv * 16 + lr;    // unit in [0,128)
    const int b0 = blk * BPW;
    const bool cell2 = (l >= 32);

    __shared__ __align__(16) char Abuf[2][BUFB];
    char* Ab = (char*)Abuf;

    // ---- weight B-fragments (resident): [gate][ktile], 8 f16 each
    f16x8 Wf[4][4], Uf[4][4];
    #pragma unroll
    for (int g = 0; g < 4; ++g) {
        #pragma unroll
        for (int kt = 0; kt < 4; ++kt) {
            f16x8 wt, ut;
            #pragma unroll
            for (int j = 0; j < 8; ++j) {
                const int krow = kt * 32 + lc * 8 + j;
                wt[j] = (f16)W[(size_t)krow * 512 + g * 128 + u];
                ut[j] = (f16)U[(size_t)krow * 512 + g * 128 + u];
            }
            Wf[g][kt] = wt;  Uf[g][kt] = ut;
        }
    }
    float bias[4];
    #pragma unroll
    for (int g = 0; g < 4; ++g) bias[g] = Bv[g * 128 + u];

    // ---- precomputed swizzled addresses (lane constants)
    const int swz = (lr & 7) << 4;
    int raddr[2][4];
    #pragma unroll
    for (int a0 = 0; a0 < 2; ++a0)
        #pragma unroll
        for (int kt = 0; kt < 4; ++kt)
            raddr[a0][kt] = (((a0 * 8 + lr) * 256) + kt * 64 + lc * 16) ^ swz;
    int waddr[4];
    #pragma unroll
    for (int e = 0; e < 4; ++e)
        waddr[e] = ((8 + 4 * lc + e) * 256 + u * 2) ^ ((((4 * lc + e) & 7)) << 4);

    // ---- init LDS: zero both buffers, load x[0] into buf0 rows 0-7
    for (int i = tid; i < 3072; i += 512) ((float*)Ab)[i] = 0.0f;
    {
        const int flat = tid * 2, xr = flat >> 7, xc = flat & 127;
        const float2 xv = *(const float2*)(X + (size_t)(b0 + xr) * (T_STEPS * UNITS) + xc);
        const int byte = ((xr * 256 + xc * 2) ^ ((xr & 7) << 4));
        *(unsigned*)(Ab + byte) = pkh(xv.x, xv.y);
    }
    __syncthreads();

    float cst[4] = {0.f, 0.f, 0.f, 0.f};   // c1 (lanes<32) / c2 (lanes>=32)

    for (int k = 0; k <= T_STEPS; ++k) {
        const int rdo = (k & 1) * BUFB, wro = BUFB - rdo;

        // issue x[k+1] prefetch early (hides HBM latency under MFMA phase)
        float xa = 0.f, xb = 0.f; int xr = 0, xc = 0;
        if (k + 1 < T_STEPS) {
            const int flat = tid * 2; xr = flat >> 7; xc = flat & 127;
            const float2 xv = *(const float2*)(X + (size_t)(b0 + xr) * (T_STEPS * UNITS)
                                                 + (size_t)(k + 1) * UNITS + xc);
            xa = xv.x; xb = xv.y;
        }

        // ---- A fragments from LDS (conflict-free via swizzle)
        f16x8 A1[4], A2[4];
        #pragma unroll
        for (int kt = 0; kt < 4; ++kt) {
            A1[kt] = *(const f16x8*)(Ab + rdo + raddr[0][kt]);
            A2[kt] = *(const f16x8*)(Ab + rdo + raddr[1][kt]);
        }

        // ---- MFMA: acc rows 0-7 = z1, rows 8-15 = z2
        f32x4 acc[4];
        #pragma unroll
        for (int g = 0; g < 4; ++g) acc[g] = f32x4{0.f, 0.f, 0.f, 0.f};
        #pragma unroll
        for (int kt = 0; kt < 4; ++kt)
            #pragma unroll
            for (int g = 0; g < 4; ++g)
                acc[g] = __builtin_amdgcn_mfma_f32_16x16x32_f16(A1[kt], Wf[g][kt], acc[g], 0, 0, 0);
        #pragma unroll
        for (int kt = 0; kt < 4; ++kt)
            #pragma unroll
            for (int g = 0; g < 4; ++g)
                acc[g] = __builtin_amdgcn_mfma_f32_16x16x32_f16(A2[kt], Uf[g][kt], acc[g], 0, 0, 0);

        // ---- epilogue: lanes<32 cell1 (k<T), lanes>=32 cell2 (k>0)
        const bool active = cell2 ? (k > 0) : (k < T_STEPS);
        float hq[4];
        #pragma unroll
        for (int e = 0; e < 4; ++e) {
            const float zi = acc[0][e] + bias[0];
            const float zf = acc[1][e] + bias[1];
            const float zg = acc[2][e] + bias[2];
            const float zo = acc[3][e] + bias[3];
            const float ig = sigmoidf_(zi), fg = sigmoidf_(zf);
            const float gg = tanhf_(zg),    og = sigmoidf_(zo);
            const float cn = fg * cst[e] + ig * gg;
            if (active) cst[e] = cn;
            hq[e] = og * tanhf_(cn);
        }

        // ---- write h1/h2 to wr buffer (row = 8 + 4*lc + e for both halves)
        if (active && k < T_STEPS) {
            #pragma unroll
            for (int e = 0; e < 4; ++e)
                *(f16*)(Ab + wro + waddr[e]) = (f16)hq[e];
        }
        // ---- write x[k+1] to wr buffer rows 0-7
        if (k + 1 < T_STEPS) {
            const int byte = ((xr * 256 + xc * 2) ^ ((xr & 7) << 4));
            *(unsigned*)(Ab + wro + byte) = pkh(xa, xb);
        }

        // ---- final outputs
        if (k == T_STEPS - 1 && !cell2) {
            #pragma unroll
            for (int e = 0; e < 4; ++e)
                out[OUT_C1 + (size_t)(b0 + 4 * lc + e) * UNITS + u] = cst[e];
        }
        if (k == T_STEPS && cell2) {
            #pragma unroll
            for (int e = 0; e < 4; ++e)
                out[(size_t)(b0 + 4 * lc + e - 8) * UNITS + u] = hq[e];
        }
        __syncthreads();
    }
}

extern "C" void kernel_launch(void* const* d_in, const int* in_sizes, int n_in,
                              void* d_out, int out_size, void* d_ws, size_t ws_size,
                              hipStream_t stream) {
    const float* X  = (const float*)d_in[0];
    const float* W  = (const float*)d_in[1];
    const float* U  = (const float*)d_in[2];
    const float* Bv = (const float*)d_in[3];
    float* out = (float*)d_out;
    hipLaunchKernelGGL(lstm2_kernel, dim3(NBLK), dim3(512), 0, stream,
                       X, W, U, Bv, out);
}